// Round 17
// baseline (51.047 us; speedup 1.0000x reference)
//
#include <hip/hip_runtime.h>

#define NROWS 8192
#define NHALF 4096
#define DIM   256
#define NB_PREP 512
#define ROWS_PER_WAVE 4       // 8192 / (512 blocks * 4 waves)
#define NTILES  64            // 8192 / 128
#define NBLK    2080          // NTILES*(NTILES+1)/2 upper-triangular blocks

typedef __attribute__((ext_vector_type(2))) float f32x2;
typedef __attribute__((ext_vector_type(4))) float f32x4;
typedef __attribute__((ext_vector_type(4))) int   v4i;
typedef __attribute__((ext_vector_type(8))) int   v8i;

__device__ __forceinline__ const float* side_base(const float* src, const float* tgt, int row) {
    return (row < NHALF) ? (src + (size_t)row * DIM)
                         : (tgt + (size_t)(row - NHALF) * DIM);
}

// Pass 1: fp32 -> fp8 e4m3 quantized copy F8; per-row sumsq sq[] (fp32, exact);
// per-block column-sum partials (transposed for bw's float4 reads) + sumsq.
// 512 blocks -> 2 waves/SIMD (was 1), and the 4 rows/wave are software-
// pipelined: all 4 loads issued first (ILP hides ~3 of 4 HBM latencies), then
// the 4 shuffle-reduce butterflies run interleaved (independent chains).
__global__ __launch_bounds__(256) void prep_kernel(
        const float* __restrict__ src, const float* __restrict__ tgt,
        unsigned char* __restrict__ F8,
        float* __restrict__ sq, float* __restrict__ colpart, float* __restrict__ sqpart)
{
    int t = threadIdx.x;
    int lane = t & 63;
    int w = t >> 6;
    int wave = blockIdx.x * 4 + w;

    // Batch all row loads (rows wave + i*2048, static unroll -> registers).
    float4 v[ROWS_PER_WAVE];
    #pragma unroll
    for (int i = 0; i < ROWS_PER_WAVE; ++i) {
        const float* p = side_base(src, tgt, wave + i * (NB_PREP * 4));
        v[i] = *(const float4*)(p + 4 * lane);
    }

    // Column sums + fp8 convert/store + per-row squared norms.
    float cs0 = 0, cs1 = 0, cs2 = 0, cs3 = 0;
    float d[ROWS_PER_WAVE];
    #pragma unroll
    for (int i = 0; i < ROWS_PER_WAVE; ++i) {
        int r = wave + i * (NB_PREP * 4);
        cs0 += v[i].x; cs1 += v[i].y; cs2 += v[i].z; cs3 += v[i].w;
        int p01 = __builtin_amdgcn_cvt_pk_fp8_f32(v[i].x, v[i].y, 0, false);
        int pk  = __builtin_amdgcn_cvt_pk_fp8_f32(v[i].z, v[i].w, p01, true);
        *(unsigned*)(F8 + (size_t)r * DIM + 4 * lane) = (unsigned)pk;
        d[i] = v[i].x * v[i].x + v[i].y * v[i].y + v[i].z * v[i].z + v[i].w * v[i].w;
    }

    // Interleaved butterflies: 4 independent reduce chains share the latency.
    #pragma unroll
    for (int off = 32; off > 0; off >>= 1) {
        #pragma unroll
        for (int i = 0; i < ROWS_PER_WAVE; ++i)
            d[i] += __shfl_xor(d[i], off);
    }
    double lss = 0.0;
    if (lane == 0) {
        #pragma unroll
        for (int i = 0; i < ROWS_PER_WAVE; ++i) {
            sq[wave + i * (NB_PREP * 4)] = d[i];
            lss += (double)d[i];
        }
    }

    __shared__ float csh[4][256];
    __shared__ double ssh[4];
    csh[w][4 * lane + 0] = cs0; csh[w][4 * lane + 1] = cs1;
    csh[w][4 * lane + 2] = cs2; csh[w][4 * lane + 3] = cs3;
    if (lane == 0) ssh[w] = lss;
    __syncthreads();
    colpart[t * NB_PREP + blockIdx.x] = csh[0][t] + csh[1][t] + csh[2][t] + csh[3][t];
    if (t == 0) sqpart[blockIdx.x] = (float)(ssh[0] + ssh[1] + ssh[2] + ssh[3]);
}

// Pass 2 (tiny): bandwidth via sum(dist) = 2*ns*sumsq - 2*||colsum||^2 (fp64),
// then the single exp2 constant q = log2(e) / (16*bw). Transposed colpart ->
// each thread reads its column's 512 partials as 128 contiguous float4 loads.
__global__ void bw_kernel(const float* __restrict__ colpart,
                          const float* __restrict__ sqpart, float* __restrict__ qconst)
{
    __shared__ double red[256], red2[256];
    int t = threadIdx.x;
    float s = 0.f;
    #pragma unroll 8
    for (int i = 0; i < NB_PREP / 4; ++i) {
        float4 v = *(const float4*)(colpart + t * NB_PREP + 4 * i);
        s += (v.x + v.y) + (v.z + v.w);
    }
    double sd = (double)s;
    red[t] = sd * sd;
    double s2 = 0.0;
    for (int b = t; b < NB_PREP; b += 256) s2 += (double)sqpart[b];
    red2[t] = s2;
    __syncthreads();
    for (int k = 128; k > 0; k >>= 1) {
        if (t < k) { red[t] += red[t + k]; red2[t] += red2[t + k]; }
        __syncthreads();
    }
    if (t == 0) {
        double ns = (double)NROWS;
        double sumdist = 2.0 * ns * red2[0] - 2.0 * red[0];
        double bw = sumdist / (ns * ns - ns) / 4.0;   // KERNEL_MUL^(KERNEL_NUM//2)=4
        qconst[0] = (float)(1.4426950408889634 / (16.0 * bw));
    }
}

__device__ __forceinline__ int tri_cum(int b) {   // # tiles before row b
    return b * NTILES - ((b * (b - 1)) >> 1);
}

// Load one 32-byte (K=128 fp8) fragment from a swizzled 128x128B LDS tile.
__device__ __forceinline__ v8i load_frag(const char* base, int r, int kbase) {
    int sw = (r & 7) << 4;
    v4i lo = *(const v4i*)(base + (r << 7) + (kbase ^ sw));
    v4i hi = *(const v4i*)(base + (r << 7) + ((kbase + 16) ^ sw));
    v8i out;
    out[0] = lo[0]; out[1] = lo[1]; out[2] = lo[2]; out[3] = lo[3];
    out[4] = hi[0]; out[5] = hi[1]; out[6] = hi[2]; out[7] = hi[3];
    return out;
}

__device__ __forceinline__ f32x4 mfma_k128(v8i a, v8i b, f32x4 c) {
#if __has_builtin(__builtin_amdgcn_mfma_scale_f32_16x16x128_f8f6f4)
    // fp8 e4m3 A/B (fmt 0), all block scales = E8M0 127 = x1.0 -> exact fp8 dot.
    return __builtin_amdgcn_mfma_scale_f32_16x16x128_f8f6f4(
        a, b, c, 0, 0, 0, 0x7F7F7F7F, 0, 0x7F7F7F7F);
#else
    const long long* av = (const long long*)&a;
    const long long* bv = (const long long*)&b;
    #pragma unroll
    for (int i = 0; i < 4; ++i)
        c = __builtin_amdgcn_mfma_f32_16x16x32_fp8_fp8(av[i], bv[i], c, 0, 0, 0);
    return c;
#endif
}

// Pass 3: staged fp8 MFMA Gram GEMM with fused MMD epilogue. R12-EXACT
// (frozen): 128x128 tile / 4 waves (2x2) / MX fp8 16x16x128 / K=256 in two
// 128-wide staged phases / 32KB LDS / lb(256,4) -> 4 blocks/CU. Measured
// optimum; all 11 structural neighbors regress (see round journal). Epilogue
// constants MUST load after the MFMA loop (R15: hoisting -> VGPR 64 + 58MB
// scratch spill).
__global__ __launch_bounds__(256, 4) void mmd_main_kernel(
        const unsigned char* __restrict__ F8, const float* __restrict__ sq,
        const float* __restrict__ qc, float* __restrict__ partials)
{
    __shared__ alignas(16) char lds[32768];   // A tile 16KB | B tile 16KB
    __shared__ float fred[4];

    int wg = blockIdx.x;
    int rank = (wg & 7) * (NBLK / 8) + (wg >> 3);
    // decode rank -> (by, bx) in the upper triangle (by <= bx), row-major
    int by = (int)((129.0f - sqrtf(16641.0f - 8.0f * (float)rank)) * 0.5f);
    while (tri_cum(by + 1) <= rank) ++by;
    while (tri_cum(by) > rank) --by;
    int bx = by + (rank - tri_cum(by));

    int t = threadIdx.x;
    int rowBase = by * 128, colBase = bx * 128;
    int lane = t & 63, w = t >> 6;
    int wr = w >> 1, wc = w & 1;
    int kbase = (lane >> 4) << 5;     // 32B K-chunk per 16-lane group

    float q = qc[0];                  // precomputed by bw_kernel

    f32x4 acc[4][4];
    #pragma unroll
    for (int m = 0; m < 4; ++m)
        #pragma unroll
        for (int n = 0; n < 4; ++n) acc[m][n] = (f32x4)0.f;

    #pragma unroll
    for (int kc = 0; kc < 2; ++kc) {
        if (kc) __syncthreads();      // all phase-0 ds_reads done before overwrite
        // Stage A+B K-half tiles: 128 rows x 128 B each, linear LDS dest,
        // inverse-swizzled global source (involution: byte ^ ((row&7)<<4)).
        #pragma unroll
        for (int qq = 0; qq < 4; ++qq) {
            int p = qq * 4096 + t * 16;                // linear LDS byte offset
            int row = p >> 7;                          // 128 B per row
            int col = (p & 127) ^ ((row & 7) << 4);
            const char* ga = (const char*)F8 + (((size_t)(rowBase + row)) << 8) + kc * 128 + col;
            const char* gb = (const char*)F8 + (((size_t)(colBase + row)) << 8) + kc * 128 + col;
            __builtin_amdgcn_global_load_lds(
                (const __attribute__((address_space(1))) void*)ga,
                (__attribute__((address_space(3))) void*)(lds + p), 16, 0, 0);
            __builtin_amdgcn_global_load_lds(
                (const __attribute__((address_space(1))) void*)gb,
                (__attribute__((address_space(3))) void*)(lds + 16384 + p), 16, 0, 0);
        }
        __syncthreads();   // compiler drains vmcnt(0) before barrier

        v8i bf[4];
        #pragma unroll
        for (int n = 0; n < 4; ++n)
            bf[n] = load_frag(lds + 16384, wc * 64 + n * 16 + (lane & 15), kbase);
        #pragma unroll
        for (int m = 0; m < 4; ++m) {
            v8i af = load_frag(lds, wr * 64 + m * 16 + (lane & 15), kbase);
            #pragma unroll
            for (int n = 0; n < 4; ++n)
                acc[m][n] = mfma_k128(af, bf[n], acc[m][n]);
        }
    }

    // Fused epilogue: e4 = exp2(-dist*q) then 4 squarings; packed-f32 pairs.
    // Constants loaded HERE (after the K-loop) - see header comment.
    f32x2 twoq2 = {2.f * q, 2.f * q};
    int rsub = (lane >> 4) * 4, csub = lane & 15;
    f32x2 nqa2[4][2];
    float qb[4];
    #pragma unroll
    for (int m = 0; m < 4; ++m)
        #pragma unroll
        for (int p = 0; p < 2; ++p) {
            int rr = rowBase + wr * 64 + m * 16 + rsub + 2 * p;
            nqa2[m][p] = (f32x2){-q * sq[rr], -q * sq[rr + 1]};
        }
    #pragma unroll
    for (int n = 0; n < 4; ++n)
        qb[n] = q * sq[colBase + wc * 64 + n * 16 + csub];

    f32x2 psum2 = {0.f, 0.f};
    #pragma unroll
    for (int m = 0; m < 4; ++m) {
        #pragma unroll
        for (int n = 0; n < 4; ++n) {
            f32x2 qbn = {qb[n], qb[n]};
            #pragma unroll
            for (int p = 0; p < 2; ++p) {
                f32x2 acc2 = {acc[m][n][2 * p], acc[m][n][2 * p + 1]};
                f32x2 arg = acc2 * twoq2 + (nqa2[m][p] - qbn);
                f32x2 e4 = {__builtin_amdgcn_exp2f(arg.x), __builtin_amdgcn_exp2f(arg.y)};
                f32x2 e3 = e4 * e4, e2 = e3 * e3, e1 = e2 * e2, e0 = e1 * e1;
                psum2 += ((e4 + e3) + (e2 + e1)) + e0;
            }
        }
    }
    float psum = psum2.x + psum2.y;

    // Wave shuffle reduce, then tiny cross-wave combine.
    #pragma unroll
    for (int off = 32; off > 0; off >>= 1) psum += __shfl_xor(psum, off);
    if (lane == 0) fred[w] = psum;
    __syncthreads();
    if (t == 0) {
        float sign = ((rowBase < NHALF) == (colBase < NHALF)) ? 1.f : -1.f;
        float wgt = (bx == by) ? 1.f : 2.f;
        partials[rank] = sign * wgt * (fred[0] + fred[1] + fred[2] + fred[3]);
    }
}

// Pass 4: fp64 reduction of block partials -> final scalar.
__global__ void finalize_kernel(const float* __restrict__ partials, int n,
                                float* __restrict__ out)
{
    __shared__ double red[256];
    int t = threadIdx.x;
    double s = 0;
    for (int i = t; i < n; i += 256) s += (double)partials[i];
    red[t] = s;
    __syncthreads();
    for (int k = 128; k > 0; k >>= 1) { if (t < k) red[t] += red[t + k]; __syncthreads(); }
    if (t == 0) {
        double nn = (double)NHALF;
        out[0] = (float)(red[0] / 5.0 / (2.0 * nn * nn));
    }
}

extern "C" void kernel_launch(void* const* d_in, const int* in_sizes, int n_in,
                              void* d_out, int out_size, void* d_ws, size_t ws_size,
                              hipStream_t stream) {
    const float* src = (const float*)d_in[0];
    const float* tgt = (const float*)d_in[1];
    float* out = (float*)d_out;
    char* ws = (char*)d_ws;

    // ws layout (~3.1 MB total):
    float*         colpart  = (float*)(ws + 0);        // 256*512*4 = 512 KB (transposed)
    float*         sqpart   = (float*)(ws + 524288);   // 512*4
    float*         qconst   = (float*)(ws + 526336);   // 4
    float*         sq       = (float*)(ws + 528384);   // 8192*4 = 32 KB
    float*         partials = (float*)(ws + 561152);   // 2080*4
    unsigned char* F8       = (unsigned char*)(ws + 1048576);  // 8192*256 = 2 MB

    prep_kernel<<<NB_PREP, 256, 0, stream>>>(src, tgt, F8, sq, colpart, sqpart);
    bw_kernel<<<1, 256, 0, stream>>>(colpart, sqpart, qconst);
    mmd_main_kernel<<<NBLK, 256, 0, stream>>>(F8, sq, qconst, partials);
    finalize_kernel<<<1, 256, 0, stream>>>(partials, NBLK, out);
}

// Round 18
// 44.503 us; speedup vs baseline: 1.1470x; 1.1470x over previous
//
#include <hip/hip_runtime.h>

#define NROWS 8192
#define NHALF 4096
#define DIM   256
#define NB_PREP 256
#define NTILES  64            // 8192 / 128
#define NBLK    2080          // NTILES*(NTILES+1)/2 upper-triangular blocks

typedef __attribute__((ext_vector_type(2))) float f32x2;
typedef __attribute__((ext_vector_type(4))) float f32x4;
typedef __attribute__((ext_vector_type(4))) int   v4i;
typedef __attribute__((ext_vector_type(8))) int   v8i;

__device__ __forceinline__ const float* side_base(const float* src, const float* tgt, int row) {
    return (row < NHALF) ? (src + (size_t)row * DIM)
                         : (tgt + (size_t)(row - NHALF) * DIM);
}

// Pass 1: fp32 -> fp8 e4m3 quantized copy F8; per-row sumsq sq[] (fp32, exact);
// per-block column-sum partials (TRANSPOSED: colpart[col*NB_PREP+block] so
// bw_kernel reads contiguous float4) + sumsq partials.
// FROZEN at the R12 form: 256 blocks / 8 rows/wave streaming. Both attempted
// "improvements" regressed: R7 atomics (+30us), R17 512-block batched (+6.3us).
__global__ __launch_bounds__(256) void prep_kernel(
        const float* __restrict__ src, const float* __restrict__ tgt,
        unsigned char* __restrict__ F8,
        float* __restrict__ sq, float* __restrict__ colpart, float* __restrict__ sqpart)
{
    int t = threadIdx.x;
    int lane = t & 63;
    int w = t >> 6;
    int wave = blockIdx.x * 4 + w;
    float cs0 = 0, cs1 = 0, cs2 = 0, cs3 = 0;
    double lss = 0.0;
    for (int r = wave; r < NROWS; r += NB_PREP * 4) {
        const float* p = side_base(src, tgt, r);
        float4 v = *(const float4*)(p + 4 * lane);
        cs0 += v.x; cs1 += v.y; cs2 += v.z; cs3 += v.w;
        int p01 = __builtin_amdgcn_cvt_pk_fp8_f32(v.x, v.y, 0, false);
        int pk  = __builtin_amdgcn_cvt_pk_fp8_f32(v.z, v.w, p01, true);
        *(unsigned*)(F8 + (size_t)r * DIM + 4 * lane) = (unsigned)pk;
        float d = v.x * v.x + v.y * v.y + v.z * v.z + v.w * v.w;
        #pragma unroll
        for (int off = 32; off > 0; off >>= 1) d += __shfl_xor(d, off);
        if (lane == 0) { sq[r] = d; lss += (double)d; }
    }
    __shared__ float csh[4][256];
    __shared__ double ssh[4];
    csh[w][4 * lane + 0] = cs0; csh[w][4 * lane + 1] = cs1;
    csh[w][4 * lane + 2] = cs2; csh[w][4 * lane + 3] = cs3;
    if (lane == 0) ssh[w] = lss;
    __syncthreads();
    colpart[t * NB_PREP + blockIdx.x] = csh[0][t] + csh[1][t] + csh[2][t] + csh[3][t];
    if (t == 0) sqpart[blockIdx.x] = (float)(ssh[0] + ssh[1] + ssh[2] + ssh[3]);
}

// Pass 2 (tiny): bandwidth via sum(dist) = 2*ns*sumsq - 2*||colsum||^2 (fp64),
// then the single exp2 constant q = log2(e) / (16*bw). Transposed colpart ->
// each thread reads its column's 256 partials as 64 contiguous float4 loads.
__global__ void bw_kernel(const float* __restrict__ colpart,
                          const float* __restrict__ sqpart, float* __restrict__ qconst)
{
    __shared__ double red[256], red2[256];
    int t = threadIdx.x;
    float s = 0.f;
    #pragma unroll 8
    for (int i = 0; i < NB_PREP / 4; ++i) {
        float4 v = *(const float4*)(colpart + t * NB_PREP + 4 * i);
        s += (v.x + v.y) + (v.z + v.w);
    }
    double sd = (double)s;
    red[t] = sd * sd;
    red2[t] = (double)sqpart[t];   // NB_PREP == 256
    __syncthreads();
    for (int k = 128; k > 0; k >>= 1) {
        if (t < k) { red[t] += red[t + k]; red2[t] += red2[t + k]; }
        __syncthreads();
    }
    if (t == 0) {
        double ns = (double)NROWS;
        double sumdist = 2.0 * ns * red2[0] - 2.0 * red[0];
        double bw = sumdist / (ns * ns - ns) / 4.0;   // KERNEL_MUL^(KERNEL_NUM//2)=4
        qconst[0] = (float)(1.4426950408889634 / (16.0 * bw));
    }
}

__device__ __forceinline__ int tri_cum(int b) {   // # tiles before row b
    return b * NTILES - ((b * (b - 1)) >> 1);
}

// Load one 32-byte (K=128 fp8) fragment from a swizzled 128x128B LDS tile.
__device__ __forceinline__ v8i load_frag(const char* base, int r, int kbase) {
    int sw = (r & 7) << 4;
    v4i lo = *(const v4i*)(base + (r << 7) + (kbase ^ sw));
    v4i hi = *(const v4i*)(base + (r << 7) + ((kbase + 16) ^ sw));
    v8i out;
    out[0] = lo[0]; out[1] = lo[1]; out[2] = lo[2]; out[3] = lo[3];
    out[4] = hi[0]; out[5] = hi[1]; out[6] = hi[2]; out[7] = hi[3];
    return out;
}

__device__ __forceinline__ f32x4 mfma_k128(v8i a, v8i b, f32x4 c) {
#if __has_builtin(__builtin_amdgcn_mfma_scale_f32_16x16x128_f8f6f4)
    // fp8 e4m3 A/B (fmt 0), all block scales = E8M0 127 = x1.0 -> exact fp8 dot.
    return __builtin_amdgcn_mfma_scale_f32_16x16x128_f8f6f4(
        a, b, c, 0, 0, 0, 0x7F7F7F7F, 0, 0x7F7F7F7F);
#else
    const long long* av = (const long long*)&a;
    const long long* bv = (const long long*)&b;
    #pragma unroll
    for (int i = 0; i < 4; ++i)
        c = __builtin_amdgcn_mfma_f32_16x16x32_fp8_fp8(av[i], bv[i], c, 0, 0, 0);
    return c;
#endif
}

// Pass 3: staged fp8 MFMA Gram GEMM with fused MMD epilogue. R12-EXACT
// (frozen, twice-reproduced at 44.75us total): 128x128 tile / 4 waves (2x2) /
// MX fp8 16x16x128 / K=256 in two 128-wide staged phases / 32KB LDS /
// lb(256,4) -> 4 blocks/CU. Measured optimum; all 12 structural neighbors
// regress: 5/CU (+1.4), 3/CU (+4.7), persistent 2/CU (+3), 64KB 1-stage (+6),
// 64^2 tiles (+9.8), B-from-L2 (+8..23), atomic prep (+30),
// sq-prefetch-above-K-loop (+19.5: VGPR collapse + 58MB scratch spill).
__global__ __launch_bounds__(256, 4) void mmd_main_kernel(
        const unsigned char* __restrict__ F8, const float* __restrict__ sq,
        const float* __restrict__ qc, float* __restrict__ partials)
{
    __shared__ alignas(16) char lds[32768];   // A tile 16KB | B tile 16KB
    __shared__ float fred[4];

    int wg = blockIdx.x;
    int rank = (wg & 7) * (NBLK / 8) + (wg >> 3);
    // decode rank -> (by, bx) in the upper triangle (by <= bx), row-major
    int by = (int)((129.0f - sqrtf(16641.0f - 8.0f * (float)rank)) * 0.5f);
    while (tri_cum(by + 1) <= rank) ++by;
    while (tri_cum(by) > rank) --by;
    int bx = by + (rank - tri_cum(by));

    int t = threadIdx.x;
    int rowBase = by * 128, colBase = bx * 128;
    int lane = t & 63, w = t >> 6;
    int wr = w >> 1, wc = w & 1;
    int kbase = (lane >> 4) << 5;     // 32B K-chunk per 16-lane group

    float q = qc[0];                  // precomputed by bw_kernel

    f32x4 acc[4][4];
    #pragma unroll
    for (int m = 0; m < 4; ++m)
        #pragma unroll
        for (int n = 0; n < 4; ++n) acc[m][n] = (f32x4)0.f;

    #pragma unroll
    for (int kc = 0; kc < 2; ++kc) {
        if (kc) __syncthreads();      // all phase-0 ds_reads done before overwrite
        // Stage A+B K-half tiles: 128 rows x 128 B each, linear LDS dest,
        // inverse-swizzled global source (involution: byte ^ ((row&7)<<4)).
        #pragma unroll
        for (int qq = 0; qq < 4; ++qq) {
            int p = qq * 4096 + t * 16;                // linear LDS byte offset
            int row = p >> 7;                          // 128 B per row
            int col = (p & 127) ^ ((row & 7) << 4);
            const char* ga = (const char*)F8 + (((size_t)(rowBase + row)) << 8) + kc * 128 + col;
            const char* gb = (const char*)F8 + (((size_t)(colBase + row)) << 8) + kc * 128 + col;
            __builtin_amdgcn_global_load_lds(
                (const __attribute__((address_space(1))) void*)ga,
                (__attribute__((address_space(3))) void*)(lds + p), 16, 0, 0);
            __builtin_amdgcn_global_load_lds(
                (const __attribute__((address_space(1))) void*)gb,
                (__attribute__((address_space(3))) void*)(lds + 16384 + p), 16, 0, 0);
        }
        __syncthreads();   // compiler drains vmcnt(0) before barrier

        v8i bf[4];
        #pragma unroll
        for (int n = 0; n < 4; ++n)
            bf[n] = load_frag(lds + 16384, wc * 64 + n * 16 + (lane & 15), kbase);
        #pragma unroll
        for (int m = 0; m < 4; ++m) {
            v8i af = load_frag(lds, wr * 64 + m * 16 + (lane & 15), kbase);
            #pragma unroll
            for (int n = 0; n < 4; ++n)
                acc[m][n] = mfma_k128(af, bf[n], acc[m][n]);
        }
    }

    // Fused epilogue: e4 = exp2(-dist*q) then 4 squarings; packed-f32 pairs.
    // Constants loaded HERE (after the K-loop) - see header comment.
    f32x2 twoq2 = {2.f * q, 2.f * q};
    int rsub = (lane >> 4) * 4, csub = lane & 15;
    f32x2 nqa2[4][2];
    float qb[4];
    #pragma unroll
    for (int m = 0; m < 4; ++m)
        #pragma unroll
        for (int p = 0; p < 2; ++p) {
            int rr = rowBase + wr * 64 + m * 16 + rsub + 2 * p;
            nqa2[m][p] = (f32x2){-q * sq[rr], -q * sq[rr + 1]};
        }
    #pragma unroll
    for (int n = 0; n < 4; ++n)
        qb[n] = q * sq[colBase + wc * 64 + n * 16 + csub];

    f32x2 psum2 = {0.f, 0.f};
    #pragma unroll
    for (int m = 0; m < 4; ++m) {
        #pragma unroll
        for (int n = 0; n < 4; ++n) {
            f32x2 qbn = {qb[n], qb[n]};
            #pragma unroll
            for (int p = 0; p < 2; ++p) {
                f32x2 acc2 = {acc[m][n][2 * p], acc[m][n][2 * p + 1]};
                f32x2 arg = acc2 * twoq2 + (nqa2[m][p] - qbn);
                f32x2 e4 = {__builtin_amdgcn_exp2f(arg.x), __builtin_amdgcn_exp2f(arg.y)};
                f32x2 e3 = e4 * e4, e2 = e3 * e3, e1 = e2 * e2, e0 = e1 * e1;
                psum2 += ((e4 + e3) + (e2 + e1)) + e0;
            }
        }
    }
    float psum = psum2.x + psum2.y;

    // Wave shuffle reduce, then tiny cross-wave combine.
    #pragma unroll
    for (int off = 32; off > 0; off >>= 1) psum += __shfl_xor(psum, off);
    if (lane == 0) fred[w] = psum;
    __syncthreads();
    if (t == 0) {
        float sign = ((rowBase < NHALF) == (colBase < NHALF)) ? 1.f : -1.f;
        float wgt = (bx == by) ? 1.f : 2.f;
        partials[rank] = sign * wgt * (fred[0] + fred[1] + fred[2] + fred[3]);
    }
}

// Pass 4: fp64 reduction of block partials -> final scalar.
__global__ void finalize_kernel(const float* __restrict__ partials, int n,
                                float* __restrict__ out)
{
    __shared__ double red[256];
    int t = threadIdx.x;
    double s = 0;
    for (int i = t; i < n; i += 256) s += (double)partials[i];
    red[t] = s;
    __syncthreads();
    for (int k = 128; k > 0; k >>= 1) { if (t < k) red[t] += red[t + k]; __syncthreads(); }
    if (t == 0) {
        double nn = (double)NHALF;
        out[0] = (float)(red[0] / 5.0 / (2.0 * nn * nn));
    }
}

extern "C" void kernel_launch(void* const* d_in, const int* in_sizes, int n_in,
                              void* d_out, int out_size, void* d_ws, size_t ws_size,
                              hipStream_t stream) {
    const float* src = (const float*)d_in[0];
    const float* tgt = (const float*)d_in[1];
    float* out = (float*)d_out;
    char* ws = (char*)d_ws;

    // ws layout (~2.6 MB total):
    float*         colpart  = (float*)(ws + 0);        // 256*256*4 = 256 KB (transposed)
    float*         sqpart   = (float*)(ws + 262144);   // 256*4
    float*         qconst   = (float*)(ws + 263168);   // 4
    float*         sq       = (float*)(ws + 264192);   // 8192*4 = 32 KB
    float*         partials = (float*)(ws + 297984);   // 2080*4
    unsigned char* F8       = (unsigned char*)(ws + 524288);  // 8192*256 = 2 MB

    prep_kernel<<<NB_PREP, 256, 0, stream>>>(src, tgt, F8, sq, colpart, sqpart);
    bw_kernel<<<1, 256, 0, stream>>>(colpart, sqpart, qconst);
    mmd_main_kernel<<<NBLK, 256, 0, stream>>>(F8, sq, qconst, partials);
    finalize_kernel<<<1, 256, 0, stream>>>(partials, NBLK, out);
}